// Round 12
// baseline (2191.810 us; speedup 1.0000x reference)
//
#include <hip/hip_runtime.h>
#include <cmath>

constexpr int kN = 1024;
constexpr int kB = 64;
constexpr int kT = 12;
constexpr int kH = 64;
constexpr int kE = 16;
constexpr long long OUT0 = (long long)kB * kT * kN * kH;  // 50331648
constexpr long long BNH = (long long)kB * kN * kH;        // 4194304

typedef __attribute__((ext_vector_type(8))) __bf16 bf16x8;
typedef __attribute__((ext_vector_type(4))) float f32x4;
typedef unsigned short u16;

struct StepPtrs {
  const u16* s0;
  const u16* s1;
  const u16* zr;
  const float* x;
  const u16* ax;
  const u16* d1;
  const u16* d2;
  const u16* d3;
};

__device__ __forceinline__ float sig_(float v) { return 1.f / (1.f + expf(-v)); }

__device__ __forceinline__ u16 f2bf(float f) {
  unsigned u = __float_as_uint(f);
  unsigned r = u + 0x7FFFu + ((u >> 16) & 1u);
  return (u16)(r >> 16);
}
__device__ __forceinline__ float bf2f(u16 s) {
  return __uint_as_float(((unsigned)s) << 16);
}

__device__ __forceinline__ void gload16(const void* g, void* l) {
  __builtin_amdgcn_global_load_lds((const __attribute__((address_space(1))) void*)g,
                                   (__attribute__((address_space(3))) void*)l, 16, 0, 0);
}

__device__ __forceinline__ ushort4 mulbf4(ushort4 a, ushort4 b) {
  ushort4 r;
  r.x = f2bf(bf2f(a.x) * bf2f(b.x));
  r.y = f2bf(bf2f(a.y) * bf2f(b.y));
  r.z = f2bf(bf2f(a.z) * bf2f(b.z));
  r.w = f2bf(bf2f(a.w) * bf2f(b.w));
  return r;
}

// ---- fp32 -> bf16 bulk convert (init states) --------------------------------
__global__ void __launch_bounds__(256) cvt_state(const float* __restrict__ in,
                                                 u16* __restrict__ out) {
  int i = (blockIdx.x * 256 + threadIdx.x) * 4;
  float4 v = *(const float4*)&in[i];
  ushort4 h;
  h.x = f2bf(v.x); h.y = f2bf(v.y); h.z = f2bf(v.z); h.w = f2bf(v.w);
  *(ushort4*)&out[i] = h;
}

// ---- A = softmax(relu(E E^T), axis=1) -> row-major bf16 --------------------
__global__ void __launch_bounds__(256) compute_A(const float* __restrict__ E,
                                                 u16* __restrict__ Ah) {
  int n = blockIdx.x, tx = threadIdx.x;
  __shared__ float En[kE];
  __shared__ float red[4];
  if (tx < kE) En[tx] = E[n * kE + tx];
  __syncthreads();
  float v[4];
  float mx = 0.f;
#pragma unroll
  for (int i = 0; i < 4; ++i) {
    int m = tx + i * 256;
    float s = 0.f;
#pragma unroll
    for (int d = 0; d < kE; ++d) s += En[d] * E[m * kE + d];
    s = fmaxf(s, 0.f);
    v[i] = s;
    mx = fmaxf(mx, s);
  }
#pragma unroll
  for (int off = 32; off; off >>= 1) mx = fmaxf(mx, __shfl_down(mx, off));
  int wid = tx >> 6, lane = tx & 63;
  if (lane == 0) red[wid] = mx;
  __syncthreads();
  mx = fmaxf(fmaxf(red[0], red[1]), fmaxf(red[2], red[3]));
  __syncthreads();
  float sum = 0.f;
#pragma unroll
  for (int i = 0; i < 4; ++i) {
    v[i] = expf(v[i] - mx);
    sum += v[i];
  }
#pragma unroll
  for (int off = 32; off; off >>= 1) sum += __shfl_down(sum, off);
  if (lane == 0) red[wid] = sum;
  __syncthreads();
  sum = red[0] + red[1] + red[2] + red[3];
  float inv = 1.f / sum;
#pragma unroll
  for (int i = 0; i < 4; ++i) {
    int m = tx + i * 256;
    Ah[n * kN + m] = f2bf(v[i] * inv);
  }
}

// ---- per-node weights, TRANSPOSED + PADDED bf16, layout [n][o][KIp] ---------
// lanes = consecutive ki -> 128B contiguous stores (coalesced).
__global__ void __launch_bounds__(256) mkw2(const float* __restrict__ E,
                                            const float* __restrict__ Wsrc,
                                            u16* __restrict__ Wh,
                                            int O, int KI, int KIp, int Idim, int mode) {
  int o = blockIdx.x;
  int n0 = blockIdx.y * 128;
  int ki = threadIdx.x;
  __shared__ float Es[128][kE + 1];
  for (int idx = threadIdx.x; idx < 128 * kE; idx += 256)
    Es[idx >> 4][idx & 15] = E[(n0 + (idx >> 4)) * kE + (idx & 15)];
  __syncthreads();
  if (ki >= KIp) return;
  float w[kE];
  if (ki < KI) {
    int k, i;
    if (mode == 0) {
      k = ki >> 7;
      i = ki & 127;
    } else {
      if (ki < 128) {
        k = ki >> 6;
        i = (ki & 63) + 2;
      } else {
        k = (ki - 128) >> 1;
        i = (ki - 128) & 1;
      }
    }
#pragma unroll
    for (int d = 0; d < kE; ++d) w[d] = Wsrc[((d * 2 + k) * Idim + i) * O + o];
  } else {
#pragma unroll
    for (int d = 0; d < kE; ++d) w[d] = 0.f;
  }
  for (int nn = 0; nn < 128; ++nn) {
    float acc = 0.f;
#pragma unroll
    for (int d = 0; d < kE; ++d) acc += Es[nn][d] * w[d];
    Wh[((long long)(n0 + nn) * O + o) * KIp + ki] = f2bf(acc);
  }
}

// ---- per-node biases (fp32), parallel over (n,o) ---------------------------
__global__ void __launch_bounds__(256) mkb(const float* __restrict__ E,
                                           const float* __restrict__ bsrc,
                                           float* __restrict__ out, int O) {
  int idx = blockIdx.x * 256 + threadIdx.x;
  int n = idx / O, o = idx - n * O;
  if (n >= kN) return;
  float acc = 0.f;
#pragma unroll
  for (int d = 0; d < kE; ++d) acc += E[n * kE + d] * bsrc[d * O + o];
  out[idx] = acc;
}

// ---- prep x: x[bt,m,c(2)] fp32 -> Xt bf16 [col=bt*2+c][m] (one-time) -------
__global__ void __launch_bounds__(256) prep_x(const float* __restrict__ x,
                                              u16* __restrict__ Vth) {
  int m0 = blockIdx.x * 64, bt0 = blockIdx.y * 32, tid = threadIdx.x;
  __shared__ u16 T[64][68];
  for (int idx = tid; idx < 2048; idx += 256) {
    int mi = idx & 63, j = idx >> 6;
    float2 v = *(const float2*)&x[((long long)(bt0 + j) * kN + m0 + mi) * 2];
    T[j * 2 + 0][mi] = f2bf(v.x);
    T[j * 2 + 1][mi] = f2bf(v.y);
  }
  __syncthreads();
  for (int idx = tid; idx < 1024; idx += 256) {
    int cc = idx >> 4, mi4 = (idx & 15) * 4;
    ushort4 v = *(const ushort4*)&T[cc][mi4];
    *(ushort4*)&Vth[(long long)(bt0 * 2 + cc) * kN + m0 + mi4] = v;
  }
}

// ---- prep: bf16 V[b,m,c] (opt *mul bf16) -> transposed bf16 ----------------
__global__ void __launch_bounds__(256) prep_split(const u16* __restrict__ srcA,
                                                  const u16* __restrict__ srcB,
                                                  const u16* __restrict__ mul,
                                                  u16* __restrict__ Vth) {
  int b = blockIdx.y, m0 = blockIdx.x * 64, tid = threadIdx.x;
  int z = blockIdx.z;
  const u16* src = z ? srcB : srcA;
  int colBase = z * 4096;
  __shared__ u16 T[64][68];
  for (int idx = tid; idx < 1024; idx += 256) {
    int mi = idx >> 4, c4 = (idx & 15) * 4;
    long long rowi = (long long)b * kN + m0 + mi;
    ushort4 v = *(const ushort4*)&src[rowi * 64 + c4];
    if (mul) {
      ushort4 mz = *(const ushort4*)&mul[rowi * 128 + c4];
      v = mulbf4(v, mz);
    }
    T[c4 + 0][mi] = v.x;
    T[c4 + 1][mi] = v.y;
    T[c4 + 2][mi] = v.z;
    T[c4 + 3][mi] = v.w;
  }
  __syncthreads();
  for (int idx = tid; idx < 1024; idx += 256) {
    int c = idx >> 4, mi4 = (idx & 15) * 4;
    ushort4 v = *(const ushort4*)&T[c][mi4];
    *(ushort4*)&Vth[(long long)(colBase + b * 64 + c) * kN + m0 + mi4] = v;
  }
}

// ---- diffusion GEMM (bf16, BM=128 BN=128, 2-phase double-buffered) ----------
__global__ void __launch_bounds__(512, 4) diff_gemm(const u16* __restrict__ Ah,
                                                    const u16* __restrict__ Vth,
                                                    u16* __restrict__ outp, int sh) {
  __shared__ __align__(16) u16 lds[2][8192];
  int tid = threadIdx.x;
  int lane = tid & 63;
  int q = lane >> 4, r16 = lane & 15;
  int wave = tid >> 6;
  int wm = wave >> 2, wn = wave & 3;
  int m0 = blockIdx.y * 128, n0 = blockIdx.x * 128;

  const u16* gsrc[2];
  int ldst[2];
#pragma unroll
  for (int j = 0; j < 2; ++j) {
    int ci = j * 512 + tid;
    int tile = ci >> 9, idx = ci & 511;
    int row = idx >> 2, sp = idx & 3;
    int sl = sp ^ ((row >> 1) & 3);
    const u16* s = tile ? Vth : Ah;
    int gr = (tile ? n0 : m0) + row;
    gsrc[j] = s + (long long)gr * kN + sl * 8;
    ldst[j] = ci * 8;
  }
  int aoff[4], voff[2];
#pragma unroll
  for (int fm = 0; fm < 4; ++fm) {
    int row = wm * 64 + fm * 16 + r16;
    aoff[fm] = row * 32 + (q ^ ((row >> 1) & 3)) * 8;
  }
#pragma unroll
  for (int fn = 0; fn < 2; ++fn) {
    int col = wn * 32 + fn * 16 + r16;
    voff[fn] = 4096 + col * 32 + (q ^ ((col >> 1) & 3)) * 8;
  }
  f32x4 acc[4][2];
#pragma unroll
  for (int fm = 0; fm < 4; ++fm)
#pragma unroll
    for (int fn = 0; fn < 2; ++fn) acc[fm][fn] = (f32x4){0.f, 0.f, 0.f, 0.f};

  auto STAGE = [&](int buf, int kt) {
#pragma unroll
    for (int j = 0; j < 2; ++j) gload16(gsrc[j] + kt * 32, &lds[buf][ldst[j]]);
  };
  auto COMPUTE = [&](int buf) {
    const u16* L = &lds[buf][0];
    bf16x8 ah[4], vh[2];
#pragma unroll
    for (int fm = 0; fm < 4; ++fm) ah[fm] = *(const bf16x8*)&L[aoff[fm]];
#pragma unroll
    for (int fn = 0; fn < 2; ++fn) vh[fn] = *(const bf16x8*)&L[voff[fn]];
#pragma unroll
    for (int fm = 0; fm < 4; ++fm)
#pragma unroll
      for (int fn = 0; fn < 2; ++fn)
        acc[fm][fn] =
            __builtin_amdgcn_mfma_f32_16x16x32_bf16(ah[fm], vh[fn], acc[fm][fn], 0, 0, 0);
  };

  STAGE(0, 0);
  asm volatile("s_waitcnt vmcnt(0)" ::: "memory");
  __builtin_amdgcn_s_barrier();
#pragma unroll 1
  for (int kt = 0; kt < 30; kt += 2) {
    STAGE(1, kt + 1);
    COMPUTE(0);
    asm volatile("s_waitcnt vmcnt(0)" ::: "memory");
    __builtin_amdgcn_s_barrier();
    STAGE(0, kt + 2);
    COMPUTE(1);
    asm volatile("s_waitcnt vmcnt(0)" ::: "memory");
    __builtin_amdgcn_s_barrier();
  }
  STAGE(1, 31);
  COMPUTE(0);
  asm volatile("s_waitcnt vmcnt(0)" ::: "memory");
  __builtin_amdgcn_s_barrier();
  COMPUTE(1);

  int msk = (1 << sh) - 1;
#pragma unroll
  for (int fm = 0; fm < 4; ++fm)
#pragma unroll
    for (int fn = 0; fn < 2; ++fn) {
      int nrow = m0 + wm * 64 + fm * 16 + q * 4;
      int col = n0 + wn * 32 + fn * 16 + r16;
      long long b = col >> sh;
      int c = col & msk;
#pragma unroll
      for (int r = 0; r < 4; ++r)
        outp[(((b * kN + nrow + r)) << sh) + c] = f2bf(acc[fm][fn][r]);
    }
}

// ---- diffusion GEMM v2 (bf16, BM=128 BN=256): halves A re-read for G2 ------
__global__ void __launch_bounds__(512, 2) diff_gemm2(const u16* __restrict__ Ah,
                                                     const u16* __restrict__ Vth,
                                                     u16* __restrict__ outp) {
  __shared__ __align__(16) u16 lds[2][24576];  // A: 0..8191, V: 8192..24575
  int tid = threadIdx.x;
  int lane = tid & 63;
  int q = lane >> 4, r16 = lane & 15;
  int wave = tid >> 6;
  int wm = wave >> 2, wn = wave & 3;  // 2m x 4n, wave tile 64 x 64
  int m0 = blockIdx.y * 128, n0 = blockIdx.x * 256;

  const u16* gsrc[3];
  int ldst[3];
  {  // A chunks: tid in [0,512)
    int row = tid >> 2, sp = tid & 3;
    gsrc[0] = Ah + (long long)(m0 + row) * kN + (sp ^ ((row >> 1) & 3)) * 8;
    ldst[0] = tid * 8;
  }
#pragma unroll
  for (int j = 1; j < 3; ++j) {  // V chunks: vi in [0,1024)
    int vi = (j - 1) * 512 + tid;
    int row = vi >> 2, sp = vi & 3;
    gsrc[j] = Vth + (long long)(n0 + row) * kN + (sp ^ ((row >> 1) & 3)) * 8;
    ldst[j] = 8192 + vi * 8;
  }
  int aoff[4], voff[4];
#pragma unroll
  for (int fm = 0; fm < 4; ++fm) {
    int row = wm * 64 + fm * 16 + r16;
    aoff[fm] = row * 32 + (q ^ ((row >> 1) & 3)) * 8;
  }
#pragma unroll
  for (int fn = 0; fn < 4; ++fn) {
    int col = wn * 64 + fn * 16 + r16;
    voff[fn] = 8192 + col * 32 + (q ^ ((col >> 1) & 3)) * 8;
  }
  f32x4 acc[4][4];
#pragma unroll
  for (int fm = 0; fm < 4; ++fm)
#pragma unroll
    for (int fn = 0; fn < 4; ++fn) acc[fm][fn] = (f32x4){0.f, 0.f, 0.f, 0.f};

  auto STAGE = [&](int buf, int kt) {
#pragma unroll
    for (int j = 0; j < 3; ++j) gload16(gsrc[j] + kt * 32, &lds[buf][ldst[j]]);
  };
  auto COMPUTE = [&](int buf) {
    const u16* L = &lds[buf][0];
    bf16x8 ah[4], vh[4];
#pragma unroll
    for (int fm = 0; fm < 4; ++fm) ah[fm] = *(const bf16x8*)&L[aoff[fm]];
#pragma unroll
    for (int fn = 0; fn < 4; ++fn) vh[fn] = *(const bf16x8*)&L[voff[fn]];
#pragma unroll
    for (int fm = 0; fm < 4; ++fm)
#pragma unroll
      for (int fn = 0; fn < 4; ++fn)
        acc[fm][fn] =
            __builtin_amdgcn_mfma_f32_16x16x32_bf16(ah[fm], vh[fn], acc[fm][fn], 0, 0, 0);
  };

  STAGE(0, 0);
  asm volatile("s_waitcnt vmcnt(0)" ::: "memory");
  __builtin_amdgcn_s_barrier();
#pragma unroll 1
  for (int kt = 0; kt < 30; kt += 2) {
    STAGE(1, kt + 1);
    COMPUTE(0);
    asm volatile("s_waitcnt vmcnt(0)" ::: "memory");
    __builtin_amdgcn_s_barrier();
    STAGE(0, kt + 2);
    COMPUTE(1);
    asm volatile("s_waitcnt vmcnt(0)" ::: "memory");
    __builtin_amdgcn_s_barrier();
  }
  STAGE(1, 31);
  COMPUTE(0);
  asm volatile("s_waitcnt vmcnt(0)" ::: "memory");
  __builtin_amdgcn_s_barrier();
  COMPUTE(1);

#pragma unroll
  for (int fm = 0; fm < 4; ++fm)
#pragma unroll
    for (int fn = 0; fn < 4; ++fn) {
      int nrow = m0 + wm * 64 + fm * 16 + q * 4;
      int col = n0 + wn * 64 + fn * 16 + r16;
      long long b = col >> 6;
      int c = col & 63;
#pragma unroll
      for (int r = 0; r < 4; ++r)
        outp[((b * kN + nrow + r) << 6) + c] = f2bf(acc[fm][fn][r]);
    }
}

// ---- per-node MFMA GEMM + fused gate epilogue (all-bf16 X, 1 pass) ----------
// W layout [n][o][KIp], register-prefetched before X gather.
template <int VAR, int O, int KIp>
__global__ void __launch_bounds__(256, 2) mfma_node(StepPtrs P,
                                                    const u16* __restrict__ Wh,
                                                    const float* __restrict__ bias,
                                                    u16* __restrict__ zr_out,
                                                    u16* __restrict__ state_out,
                                                    float* __restrict__ seq_out,
                                                    float* __restrict__ last_out, int t) {
  constexpr int S = KIp + 8;  // LDS row stride (elements)
  constexpr int NKT = KIp / 32;
  constexpr int NF = (O == 128) ? 2 : 1;
  __shared__ __align__(16) u16 Xs[64 * S];
  int n = blockIdx.x;
  int tid = threadIdx.x;
  int lane = tid & 63, wave = tid >> 6;
  int q = lane >> 4, r16 = lane & 15;
  int colbase = (O == 128) ? wave * 32 : wave * 16;

  // --- W register prefetch (latency hides under the X gather) ---
  bf16x8 wreg[NKT][NF];
#pragma unroll
  for (int kt = 0; kt < NKT; ++kt)
#pragma unroll
    for (int fn = 0; fn < NF; ++fn)
      wreg[kt][fn] = *(const bf16x8*)&Wh[((long long)n * O + colbase + fn * 16 + r16) * KIp +
                                         kt * 32 + q * 8];

  if constexpr (VAR == 0 || VAR == 1) {
    // X = [s0(*z) | d1 | x_t(2) | ax(2) | pad..160)
    for (int idx = tid; idx < 1024; idx += 256) {
      int b = idx >> 4, c4 = (idx & 15) << 2;
      long long bn = (long long)b * kN + n;
      ushort4 v0 = *(const ushort4*)&P.s0[bn * 64 + c4];
      if (VAR == 1) {
        ushort4 z = *(const ushort4*)&P.zr[bn * 128 + c4];
        v0 = mulbf4(v0, z);
      }
      *(ushort4*)&Xs[b * S + c4] = v0;
      ushort4 v1 = *(const ushort4*)&P.d1[bn * 64 + c4];
      *(ushort4*)&Xs[b * S + 64 + c4] = v1;
    }
    if (tid < 128) {
      int b = tid >> 1, c = tid & 1;
      long long btn = ((long long)b * kT + t) * kN + n;
      Xs[b * S + 128 + c] = f2bf(P.x[btn * 2 + c]);
      Xs[b * S + 130 + c] = P.ax[btn * 2 + c];
    }
    for (int idx = tid; idx < 448; idx += 256) {  // zero pad ki 132..159
      int b = idx / 7, c = 132 + (idx % 7) * 4;
      ushort4 zz = {0, 0, 0, 0};
      *(ushort4*)&Xs[b * S + c] = zz;
    }
  } else {
    // X = [s0 | s1(*z) | d2 | d3]  (256)
    for (int idx = tid; idx < 1024; idx += 256) {
      int b = idx >> 4, c4 = (idx & 15) << 2;
      long long bn = (long long)b * kN + n;
      ushort4 v0 = *(const ushort4*)&P.s0[bn * 64 + c4];
      *(ushort4*)&Xs[b * S + c4] = v0;
      ushort4 v1 = *(const ushort4*)&P.s1[bn * 64 + c4];
      if (VAR == 3) {
        ushort4 z = *(const ushort4*)&P.zr[bn * 128 + c4];
        v1 = mulbf4(v1, z);
      }
      *(ushort4*)&Xs[b * S + 64 + c4] = v1;
      ushort4 v2 = *(const ushort4*)&P.d2[bn * 64 + c4];
      *(ushort4*)&Xs[b * S + 128 + c4] = v2;
      ushort4 v3 = *(const ushort4*)&P.d3[bn * 64 + c4];
      *(ushort4*)&Xs[b * S + 192 + c4] = v3;
    }
  }
  __syncthreads();

  f32x4 acc[4][NF];
#pragma unroll
  for (int fm = 0; fm < 4; ++fm)
#pragma unroll
    for (int fn = 0; fn < NF; ++fn) acc[fm][fn] = (f32x4){0.f, 0.f, 0.f, 0.f};

#pragma unroll
  for (int kt = 0; kt < NKT; ++kt) {
    int kb = kt * 32 + q * 8;
    bf16x8 xh[4];
#pragma unroll
    for (int fm = 0; fm < 4; ++fm)
      xh[fm] = *(const bf16x8*)&Xs[(fm * 16 + r16) * S + kb];
#pragma unroll
    for (int fm = 0; fm < 4; ++fm)
#pragma unroll
      for (int fn = 0; fn < NF; ++fn)
        acc[fm][fn] =
            __builtin_amdgcn_mfma_f32_16x16x32_bf16(xh[fm], wreg[kt][fn], acc[fm][fn], 0, 0, 0);
  }

  if constexpr (O == 128) {  // gate: zr = sigmoid(acc + bias) -> bf16
#pragma unroll
    for (int fn = 0; fn < NF; ++fn) {
      int o = colbase + fn * 16 + r16;
      float bb = bias[n * 128 + o];
#pragma unroll
      for (int fm = 0; fm < 4; ++fm) {
#pragma unroll
        for (int r = 0; r < 4; ++r) {
          int b = fm * 16 + q * 4 + r;
          zr_out[((long long)b * kN + n) * 128 + o] = f2bf(sig_(acc[fm][fn][r] + bb));
        }
      }
    }
  } else {  // update: h = r*s + (1-r)*tanh(acc + bias)
    const u16* sptr = (VAR == 1) ? P.s0 : P.s1;
    int o = colbase + r16;
    float bb = bias[n * 64 + o];
#pragma unroll
    for (int fm = 0; fm < 4; ++fm) {
#pragma unroll
      for (int r = 0; r < 4; ++r) {
        int b = fm * 16 + q * 4 + r;
        long long bn = (long long)b * kN + n;
        float rr = bf2f(P.zr[bn * 128 + 64 + o]);
        float sv = bf2f(sptr[bn * 64 + o]);
        float h = rr * sv + (1.f - rr) * tanhf(acc[fm][0][r] + bb);
        state_out[bn * 64 + o] = f2bf(h);
        if constexpr (VAR == 3) {
          seq_out[(((long long)b * kT + t) * kN + n) * 64 + o] = h;
        }
        if (t == kT - 1) last_out[bn * 64 + o] = h;
      }
    }
  }
}

extern "C" void kernel_launch(void* const* d_in, const int* in_sizes, int n_in, void* d_out,
                              int out_size, void* d_ws, size_t ws_size, hipStream_t stream) {
  (void)in_sizes; (void)n_in; (void)out_size; (void)ws_size;
  const float* x   = (const float*)d_in[0];
  const float* ist = (const float*)d_in[1];
  const float* E   = (const float*)d_in[2];
  const float* gw0 = (const float*)d_in[3];
  const float* gb0 = (const float*)d_in[4];
  const float* uw0 = (const float*)d_in[5];
  const float* ub0 = (const float*)d_in[6];
  const float* gw1 = (const float*)d_in[7];
  const float* gb1 = (const float*)d_in[8];
  const float* uw1 = (const float*)d_in[9];
  const float* ub1 = (const float*)d_in[10];
  float* out = (float*)d_out;

  char* base = (char*)d_ws;
  size_t off = 0;
  auto alloc = [&](size_t bytes) {
    char* p = base + off;
    off += (bytes + 1023) & ~(size_t)1023;
    return p;
  };
  u16* Vth = (u16*)alloc((size_t)8192 * kN * 2);
  u16* Ahh = (u16*)alloc((size_t)kN * kN * 2);
  u16* Ax = (u16*)alloc((size_t)kB * kT * kN * 2 * 2);
  u16* Wg0h = (u16*)alloc((size_t)kN * 128 * 160 * 2);
  u16* Wu0h = (u16*)alloc((size_t)kN * 64 * 160 * 2);
  u16* Wg1h = (u16*)alloc((size_t)kN * 128 * 256 * 2);
  u16* Wu1h = (u16*)alloc((size_t)kN * 64 * 256 * 2);
  float* Bg0 = (float*)alloc((size_t)kN * 128 * 4);
  float* Bu0 = (float*)alloc((size_t)kN * 64 * 4);
  float* Bg1 = (float*)alloc((size_t)kN * 128 * 4);
  float* Bu1 = (float*)alloc((size_t)kN * 64 * 4);
  u16* ss = (u16*)alloc((size_t)BNH * 2 * 2);  // [s0 | s1] bf16
  u16* dx = (u16*)alloc((size_t)BNH * 2);
  u16* dd = (u16*)alloc((size_t)BNH * 2 * 2);  // [d2 | d3] bf16
  u16* zr = (u16*)alloc((size_t)kB * kN * 128 * 2);
  u16* s0 = ss;
  u16* s1 = ss + BNH;
  u16* d2 = dd;
  u16* d3 = dd + BNH;

  cvt_state<<<(int)(2 * BNH / 1024), 256, 0, stream>>>(ist, ss);

  compute_A<<<kN, 256, 0, stream>>>(E, Ahh);
  // x diffusion (one-time): Ax[bt,n,c] = sum_m A[n,m] x[bt,m,c]  (bf16 out)
  prep_x<<<dim3(16, 24), 256, 0, stream>>>(x, Vth);
  diff_gemm<<<dim3(12, 8), 512, 0, stream>>>(Ahh, Vth, Ax, 1);

  mkw2<<<dim3(128, 8), 256, 0, stream>>>(E, gw0, Wg0h, 128, 132, 160, 66, 1);
  mkw2<<<dim3(64, 8), 256, 0, stream>>>(E, uw0, Wu0h, 64, 132, 160, 66, 1);
  mkw2<<<dim3(128, 8), 256, 0, stream>>>(E, gw1, Wg1h, 128, 256, 256, 128, 0);
  mkw2<<<dim3(64, 8), 256, 0, stream>>>(E, uw1, Wu1h, 64, 256, 256, 128, 0);
  mkb<<<(kN * 128) / 256, 256, 0, stream>>>(E, gb0, Bg0, 128);
  mkb<<<(kN * 64) / 256, 256, 0, stream>>>(E, ub0, Bu0, 64);
  mkb<<<(kN * 128) / 256, 256, 0, stream>>>(E, gb1, Bg1, 128);
  mkb<<<(kN * 64) / 256, 256, 0, stream>>>(E, ub1, Bu1, 64);

  // bootstrap: d2 = A @ s0_init
  prep_split<<<dim3(16, kB, 1), 256, 0, stream>>>(s0, nullptr, nullptr, Vth);
  diff_gemm<<<dim3(32, 8), 512, 0, stream>>>(Ahh, Vth, d2, 6);

  for (int t = 0; t < kT; ++t) {
    // L0 gate (diffused state = d2 from previous step / bootstrap)
    StepPtrs Pg0{s0, s1, zr, x, Ax, d2, d2, d3};
    mfma_node<0, 128, 160><<<kN, 256, 0, stream>>>(Pg0, Wg0h, Bg0, zr, nullptr,
                                                   nullptr, nullptr, t);
    // G1 = A @ (z0*s0) -> dx
    prep_split<<<dim3(16, kB, 1), 256, 0, stream>>>(s0, nullptr, zr, Vth);
    diff_gemm<<<dim3(32, 8), 512, 0, stream>>>(Ahh, Vth, dx, 6);
    // L0 update: s0 <- h0; lasts[0] at t==T-1
    StepPtrs Pu0{s0, s1, zr, x, Ax, dx, d2, d3};
    mfma_node<1, 64, 160><<<kN, 256, 0, stream>>>(Pu0, Wu0h, Bu0, nullptr, s0,
                                                  nullptr, out + OUT0, t);
    // G2 = A @ [h0 ; s1] -> [d2 | d3]  (BN=256 variant: half the A re-reads)
    prep_split<<<dim3(16, kB, 2), 256, 0, stream>>>(s0, s1, nullptr, Vth);
    diff_gemm2<<<dim3(32, 8), 512, 0, stream>>>(Ahh, Vth, d2);
    // L1 gate
    StepPtrs P1g{s0, s1, zr, x, Ax, d2, d2, d3};
    mfma_node<2, 128, 256><<<kN, 256, 0, stream>>>(P1g, Wg1h, Bg1, zr, nullptr,
                                                   nullptr, nullptr, t);
    // G3 = A @ (z1*s1) -> dx
    prep_split<<<dim3(16, kB, 1), 256, 0, stream>>>(s1, nullptr, zr, Vth);
    diff_gemm<<<dim3(32, 8), 512, 0, stream>>>(Ahh, Vth, dx, 6);
    // L1 update: s1 <- h1; seq out; lasts[1] at t==T-1
    StepPtrs P1u{s0, s1, zr, x, Ax, d2, d2, dx};
    mfma_node<3, 64, 256><<<kN, 256, 0, stream>>>(P1u, Wu1h, Bu1, nullptr, s1, out,
                                                  out + OUT0 + BNH, t);
  }
}

// Round 13
// 2123.838 us; speedup vs baseline: 1.0320x; 1.0320x over previous
//
#include <hip/hip_runtime.h>
#include <cmath>

constexpr int kN = 1024;
constexpr int kB = 64;
constexpr int kT = 12;
constexpr int kH = 64;
constexpr int kE = 16;
constexpr long long OUT0 = (long long)kB * kT * kN * kH;  // 50331648
constexpr long long BNH = (long long)kB * kN * kH;        // 4194304

typedef __attribute__((ext_vector_type(8))) __bf16 bf16x8;
typedef __attribute__((ext_vector_type(4))) float f32x4;
typedef unsigned short u16;

struct StepPtrs {
  const u16* s0;
  const u16* s1;
  const u16* zr;
  const float* x;
  const u16* ax;
  const u16* d1;
  const u16* d2;
  const u16* d3;
};

__device__ __forceinline__ float sig_(float v) { return 1.f / (1.f + expf(-v)); }

__device__ __forceinline__ u16 f2bf(float f) {
  unsigned u = __float_as_uint(f);
  unsigned r = u + 0x7FFFu + ((u >> 16) & 1u);
  return (u16)(r >> 16);
}
__device__ __forceinline__ float bf2f(u16 s) {
  return __uint_as_float(((unsigned)s) << 16);
}

__device__ __forceinline__ void gload16(const void* g, void* l) {
  __builtin_amdgcn_global_load_lds((const __attribute__((address_space(1))) void*)g,
                                   (__attribute__((address_space(3))) void*)l, 16, 0, 0);
}

__device__ __forceinline__ ushort4 mulbf4(ushort4 a, ushort4 b) {
  ushort4 r;
  r.x = f2bf(bf2f(a.x) * bf2f(b.x));
  r.y = f2bf(bf2f(a.y) * bf2f(b.y));
  r.z = f2bf(bf2f(a.z) * bf2f(b.z));
  r.w = f2bf(bf2f(a.w) * bf2f(b.w));
  return r;
}

// ---- fp32 -> bf16 bulk convert (init states) --------------------------------
__global__ void __launch_bounds__(256) cvt_state(const float* __restrict__ in,
                                                 u16* __restrict__ out) {
  int i = (blockIdx.x * 256 + threadIdx.x) * 4;
  float4 v = *(const float4*)&in[i];
  ushort4 h;
  h.x = f2bf(v.x); h.y = f2bf(v.y); h.z = f2bf(v.z); h.w = f2bf(v.w);
  *(ushort4*)&out[i] = h;
}

// ---- A = softmax(relu(E E^T), axis=1) -> row-major bf16 --------------------
__global__ void __launch_bounds__(256) compute_A(const float* __restrict__ E,
                                                 u16* __restrict__ Ah) {
  int n = blockIdx.x, tx = threadIdx.x;
  __shared__ float En[kE];
  __shared__ float red[4];
  if (tx < kE) En[tx] = E[n * kE + tx];
  __syncthreads();
  float v[4];
  float mx = 0.f;
#pragma unroll
  for (int i = 0; i < 4; ++i) {
    int m = tx + i * 256;
    float s = 0.f;
#pragma unroll
    for (int d = 0; d < kE; ++d) s += En[d] * E[m * kE + d];
    s = fmaxf(s, 0.f);
    v[i] = s;
    mx = fmaxf(mx, s);
  }
#pragma unroll
  for (int off = 32; off; off >>= 1) mx = fmaxf(mx, __shfl_down(mx, off));
  int wid = tx >> 6, lane = tx & 63;
  if (lane == 0) red[wid] = mx;
  __syncthreads();
  mx = fmaxf(fmaxf(red[0], red[1]), fmaxf(red[2], red[3]));
  __syncthreads();
  float sum = 0.f;
#pragma unroll
  for (int i = 0; i < 4; ++i) {
    v[i] = expf(v[i] - mx);
    sum += v[i];
  }
#pragma unroll
  for (int off = 32; off; off >>= 1) sum += __shfl_down(sum, off);
  if (lane == 0) red[wid] = sum;
  __syncthreads();
  sum = red[0] + red[1] + red[2] + red[3];
  float inv = 1.f / sum;
#pragma unroll
  for (int i = 0; i < 4; ++i) {
    int m = tx + i * 256;
    Ah[n * kN + m] = f2bf(v[i] * inv);
  }
}

// ---- per-node weights, TRANSPOSED + PADDED bf16, layout [n][o][KIp] ---------
__global__ void __launch_bounds__(256) mkw2(const float* __restrict__ E,
                                            const float* __restrict__ Wsrc,
                                            u16* __restrict__ Wh,
                                            int O, int KI, int KIp, int Idim, int mode) {
  int o = blockIdx.x;
  int n0 = blockIdx.y * 128;
  int ki = threadIdx.x;
  __shared__ float Es[128][kE + 1];
  for (int idx = threadIdx.x; idx < 128 * kE; idx += 256)
    Es[idx >> 4][idx & 15] = E[(n0 + (idx >> 4)) * kE + (idx & 15)];
  __syncthreads();
  if (ki >= KIp) return;
  float w[kE];
  if (ki < KI) {
    int k, i;
    if (mode == 0) {
      k = ki >> 7;
      i = ki & 127;
    } else {
      if (ki < 128) {
        k = ki >> 6;
        i = (ki & 63) + 2;
      } else {
        k = (ki - 128) >> 1;
        i = (ki - 128) & 1;
      }
    }
#pragma unroll
    for (int d = 0; d < kE; ++d) w[d] = Wsrc[((d * 2 + k) * Idim + i) * O + o];
  } else {
#pragma unroll
    for (int d = 0; d < kE; ++d) w[d] = 0.f;
  }
  for (int nn = 0; nn < 128; ++nn) {
    float acc = 0.f;
#pragma unroll
    for (int d = 0; d < kE; ++d) acc += Es[nn][d] * w[d];
    Wh[((long long)(n0 + nn) * O + o) * KIp + ki] = f2bf(acc);
  }
}

// ---- per-node biases (fp32), parallel over (n,o) ---------------------------
__global__ void __launch_bounds__(256) mkb(const float* __restrict__ E,
                                           const float* __restrict__ bsrc,
                                           float* __restrict__ out, int O) {
  int idx = blockIdx.x * 256 + threadIdx.x;
  int n = idx / O, o = idx - n * O;
  if (n >= kN) return;
  float acc = 0.f;
#pragma unroll
  for (int d = 0; d < kE; ++d) acc += E[n * kE + d] * bsrc[d * O + o];
  out[idx] = acc;
}

// ---- prep x: x[bt,m,c(2)] fp32 -> Xt bf16 [col=bt*2+c][m] (one-time) -------
__global__ void __launch_bounds__(256) prep_x(const float* __restrict__ x,
                                              u16* __restrict__ Vth) {
  int m0 = blockIdx.x * 64, bt0 = blockIdx.y * 32, tid = threadIdx.x;
  __shared__ u16 T[64][68];
  for (int idx = tid; idx < 2048; idx += 256) {
    int mi = idx & 63, j = idx >> 6;
    float2 v = *(const float2*)&x[((long long)(bt0 + j) * kN + m0 + mi) * 2];
    T[j * 2 + 0][mi] = f2bf(v.x);
    T[j * 2 + 1][mi] = f2bf(v.y);
  }
  __syncthreads();
  for (int idx = tid; idx < 1024; idx += 256) {
    int cc = idx >> 4, mi4 = (idx & 15) * 4;
    ushort4 v = *(const ushort4*)&T[cc][mi4];
    *(ushort4*)&Vth[(long long)(bt0 * 2 + cc) * kN + m0 + mi4] = v;
  }
}

// ---- prep: bf16 V (opt per-source mul) -> transposed bf16 ------------------
// z-dim selects (srcA,mulA) or (srcB,mulB); colBase = z*4096.
__global__ void __launch_bounds__(256) prep_split(const u16* __restrict__ srcA,
                                                  const u16* __restrict__ srcB,
                                                  const u16* __restrict__ mulA,
                                                  const u16* __restrict__ mulB,
                                                  u16* __restrict__ Vth) {
  int b = blockIdx.y, m0 = blockIdx.x * 64, tid = threadIdx.x;
  int z = blockIdx.z;
  const u16* src = z ? srcB : srcA;
  const u16* mul = z ? mulB : mulA;
  int colBase = z * 4096;
  __shared__ u16 T[64][68];
  for (int idx = tid; idx < 1024; idx += 256) {
    int mi = idx >> 4, c4 = (idx & 15) * 4;
    long long rowi = (long long)b * kN + m0 + mi;
    ushort4 v = *(const ushort4*)&src[rowi * 64 + c4];
    if (mul) {
      ushort4 mz = *(const ushort4*)&mul[rowi * 128 + c4];
      v = mulbf4(v, mz);
    }
    T[c4 + 0][mi] = v.x;
    T[c4 + 1][mi] = v.y;
    T[c4 + 2][mi] = v.z;
    T[c4 + 3][mi] = v.w;
  }
  __syncthreads();
  for (int idx = tid; idx < 1024; idx += 256) {
    int c = idx >> 4, mi4 = (idx & 15) * 4;
    ushort4 v = *(const ushort4*)&T[c][mi4];
    *(ushort4*)&Vth[(long long)(colBase + b * 64 + c) * kN + m0 + mi4] = v;
  }
}

// ---- diffusion GEMM (bf16, BM=128 BN=128, 2-phase double-buffered) ----------
__global__ void __launch_bounds__(512, 4) diff_gemm(const u16* __restrict__ Ah,
                                                    const u16* __restrict__ Vth,
                                                    u16* __restrict__ outp, int sh) {
  __shared__ __align__(16) u16 lds[2][8192];
  int tid = threadIdx.x;
  int lane = tid & 63;
  int q = lane >> 4, r16 = lane & 15;
  int wave = tid >> 6;
  int wm = wave >> 2, wn = wave & 3;
  int m0 = blockIdx.y * 128, n0 = blockIdx.x * 128;

  const u16* gsrc[2];
  int ldst[2];
#pragma unroll
  for (int j = 0; j < 2; ++j) {
    int ci = j * 512 + tid;
    int tile = ci >> 9, idx = ci & 511;
    int row = idx >> 2, sp = idx & 3;
    int sl = sp ^ ((row >> 1) & 3);
    const u16* s = tile ? Vth : Ah;
    int gr = (tile ? n0 : m0) + row;
    gsrc[j] = s + (long long)gr * kN + sl * 8;
    ldst[j] = ci * 8;
  }
  int aoff[4], voff[2];
#pragma unroll
  for (int fm = 0; fm < 4; ++fm) {
    int row = wm * 64 + fm * 16 + r16;
    aoff[fm] = row * 32 + (q ^ ((row >> 1) & 3)) * 8;
  }
#pragma unroll
  for (int fn = 0; fn < 2; ++fn) {
    int col = wn * 32 + fn * 16 + r16;
    voff[fn] = 4096 + col * 32 + (q ^ ((col >> 1) & 3)) * 8;
  }
  f32x4 acc[4][2];
#pragma unroll
  for (int fm = 0; fm < 4; ++fm)
#pragma unroll
    for (int fn = 0; fn < 2; ++fn) acc[fm][fn] = (f32x4){0.f, 0.f, 0.f, 0.f};

  auto STAGE = [&](int buf, int kt) {
#pragma unroll
    for (int j = 0; j < 2; ++j) gload16(gsrc[j] + kt * 32, &lds[buf][ldst[j]]);
  };
  auto COMPUTE = [&](int buf) {
    const u16* L = &lds[buf][0];
    bf16x8 ah[4], vh[2];
#pragma unroll
    for (int fm = 0; fm < 4; ++fm) ah[fm] = *(const bf16x8*)&L[aoff[fm]];
#pragma unroll
    for (int fn = 0; fn < 2; ++fn) vh[fn] = *(const bf16x8*)&L[voff[fn]];
#pragma unroll
    for (int fm = 0; fm < 4; ++fm)
#pragma unroll
      for (int fn = 0; fn < 2; ++fn)
        acc[fm][fn] =
            __builtin_amdgcn_mfma_f32_16x16x32_bf16(ah[fm], vh[fn], acc[fm][fn], 0, 0, 0);
  };

  STAGE(0, 0);
  asm volatile("s_waitcnt vmcnt(0)" ::: "memory");
  __builtin_amdgcn_s_barrier();
#pragma unroll 1
  for (int kt = 0; kt < 30; kt += 2) {
    STAGE(1, kt + 1);
    COMPUTE(0);
    asm volatile("s_waitcnt vmcnt(0)" ::: "memory");
    __builtin_amdgcn_s_barrier();
    STAGE(0, kt + 2);
    COMPUTE(1);
    asm volatile("s_waitcnt vmcnt(0)" ::: "memory");
    __builtin_amdgcn_s_barrier();
  }
  STAGE(1, 31);
  COMPUTE(0);
  asm volatile("s_waitcnt vmcnt(0)" ::: "memory");
  __builtin_amdgcn_s_barrier();
  COMPUTE(1);

  int msk = (1 << sh) - 1;
#pragma unroll
  for (int fm = 0; fm < 4; ++fm)
#pragma unroll
    for (int fn = 0; fn < 2; ++fn) {
      int nrow = m0 + wm * 64 + fm * 16 + q * 4;
      int col = n0 + wn * 32 + fn * 16 + r16;
      long long b = col >> sh;
      int c = col & msk;
#pragma unroll
      for (int r = 0; r < 4; ++r)
        outp[(((b * kN + nrow + r)) << sh) + c] = f2bf(acc[fm][fn][r]);
    }
}

// ---- per-node MFMA GEMM + fused gate epilogue (device body) -----------------
template <int VAR, int O, int KIp>
__device__ __forceinline__ void mfma_body(int n, const StepPtrs& P,
                                          const u16* __restrict__ Wh,
                                          const float* __restrict__ bias,
                                          u16* __restrict__ zr_out,
                                          u16* __restrict__ state_out,
                                          float* __restrict__ seq_out,
                                          float* __restrict__ last_out, int t) {
  constexpr int S = KIp + 8;
  constexpr int NKT = KIp / 32;
  constexpr int NF = (O == 128) ? 2 : 1;
  __shared__ __align__(16) u16 Xs[64 * (256 + 8)];  // sized for max KIp
  int tid = threadIdx.x;
  int lane = tid & 63, wave = tid >> 6;
  int q = lane >> 4, r16 = lane & 15;
  int colbase = (O == 128) ? wave * 32 : wave * 16;

  bf16x8 wreg[NKT][NF];
#pragma unroll
  for (int kt = 0; kt < NKT; ++kt)
#pragma unroll
    for (int fn = 0; fn < NF; ++fn)
      wreg[kt][fn] = *(const bf16x8*)&Wh[((long long)n * O + colbase + fn * 16 + r16) * KIp +
                                         kt * 32 + q * 8];

  if constexpr (VAR == 0 || VAR == 1) {
    for (int idx = tid; idx < 1024; idx += 256) {
      int b = idx >> 4, c4 = (idx & 15) << 2;
      long long bn = (long long)b * kN + n;
      ushort4 v0 = *(const ushort4*)&P.s0[bn * 64 + c4];
      if (VAR == 1) {
        ushort4 z = *(const ushort4*)&P.zr[bn * 128 + c4];
        v0 = mulbf4(v0, z);
      }
      *(ushort4*)&Xs[b * S + c4] = v0;
      ushort4 v1 = *(const ushort4*)&P.d1[bn * 64 + c4];
      *(ushort4*)&Xs[b * S + 64 + c4] = v1;
    }
    if (tid < 128) {
      int b = tid >> 1, c = tid & 1;
      long long btn = ((long long)b * kT + t) * kN + n;
      Xs[b * S + 128 + c] = f2bf(P.x[btn * 2 + c]);
      Xs[b * S + 130 + c] = P.ax[btn * 2 + c];
    }
    for (int idx = tid; idx < 448; idx += 256) {
      int b = idx / 7, c = 132 + (idx % 7) * 4;
      ushort4 zz = {0, 0, 0, 0};
      *(ushort4*)&Xs[b * S + c] = zz;
    }
  } else {
    for (int idx = tid; idx < 1024; idx += 256) {
      int b = idx >> 4, c4 = (idx & 15) << 2;
      long long bn = (long long)b * kN + n;
      ushort4 v0 = *(const ushort4*)&P.s0[bn * 64 + c4];
      *(ushort4*)&Xs[b * S + c4] = v0;
      ushort4 v1 = *(const ushort4*)&P.s1[bn * 64 + c4];
      if (VAR == 3) {
        ushort4 z = *(const ushort4*)&P.zr[bn * 128 + c4];
        v1 = mulbf4(v1, z);
      }
      *(ushort4*)&Xs[b * S + 64 + c4] = v1;
      ushort4 v2 = *(const ushort4*)&P.d2[bn * 64 + c4];
      *(ushort4*)&Xs[b * S + 128 + c4] = v2;
      ushort4 v3 = *(const ushort4*)&P.d3[bn * 64 + c4];
      *(ushort4*)&Xs[b * S + 192 + c4] = v3;
    }
  }
  __syncthreads();

  f32x4 acc[4][NF];
#pragma unroll
  for (int fm = 0; fm < 4; ++fm)
#pragma unroll
    for (int fn = 0; fn < NF; ++fn) acc[fm][fn] = (f32x4){0.f, 0.f, 0.f, 0.f};

#pragma unroll
  for (int kt = 0; kt < NKT; ++kt) {
    int kb = kt * 32 + q * 8;
    bf16x8 xh[4];
#pragma unroll
    for (int fm = 0; fm < 4; ++fm)
      xh[fm] = *(const bf16x8*)&Xs[(fm * 16 + r16) * S + kb];
#pragma unroll
    for (int fm = 0; fm < 4; ++fm)
#pragma unroll
      for (int fn = 0; fn < NF; ++fn)
        acc[fm][fn] =
            __builtin_amdgcn_mfma_f32_16x16x32_bf16(xh[fm], wreg[kt][fn], acc[fm][fn], 0, 0, 0);
  }

  if constexpr (O == 128) {
#pragma unroll
    for (int fn = 0; fn < NF; ++fn) {
      int o = colbase + fn * 16 + r16;
      float bb = bias[n * 128 + o];
#pragma unroll
      for (int fm = 0; fm < 4; ++fm) {
#pragma unroll
        for (int r = 0; r < 4; ++r) {
          int b = fm * 16 + q * 4 + r;
          zr_out[((long long)b * kN + n) * 128 + o] = f2bf(sig_(acc[fm][fn][r] + bb));
        }
      }
    }
  } else {
    const u16* sptr = (VAR == 1) ? P.s0 : P.s1;
    int o = colbase + r16;
    float bb = bias[n * 64 + o];
#pragma unroll
    for (int fm = 0; fm < 4; ++fm) {
#pragma unroll
      for (int r = 0; r < 4; ++r) {
        int b = fm * 16 + q * 4 + r;
        long long bn = (long long)b * kN + n;
        float rr = bf2f(P.zr[bn * 128 + 64 + o]);
        float sv = bf2f(sptr[bn * 64 + o]);
        float h = rr * sv + (1.f - rr) * tanhf(acc[fm][0][r] + bb);
        state_out[bn * 64 + o] = f2bf(h);
        if constexpr (VAR == 3) {
          seq_out[(((long long)b * kT + t) * kN + n) * 64 + o] = h;
        }
        if (t == kT - 1) last_out[bn * 64 + o] = h;
      }
    }
  }
}

template <int VAR, int O, int KIp>
__global__ void __launch_bounds__(256, 2) mfma_node(StepPtrs P, const u16* __restrict__ Wh,
                                                    const float* __restrict__ bias,
                                                    u16* __restrict__ zr_out,
                                                    u16* __restrict__ state_out,
                                                    float* __restrict__ seq_out,
                                                    float* __restrict__ last_out, int t) {
  mfma_body<VAR, O, KIp>(blockIdx.x, P, Wh, bias, zr_out, state_out, seq_out, last_out, t);
}

// ---- merged gates: blocks [0,kN) = L1 gate (VAR2), [kN,2kN) = L0 gate t+1 --
__global__ void __launch_bounds__(256, 2) gate_pair(StepPtrs Pa, const u16* __restrict__ Wa,
                                                    const float* __restrict__ Ba,
                                                    u16* __restrict__ zra,
                                                    StepPtrs Pb, const u16* __restrict__ Wb,
                                                    const float* __restrict__ Bb,
                                                    u16* __restrict__ zrb, int tb) {
  if (blockIdx.x < kN)
    mfma_body<2, 128, 256>(blockIdx.x, Pa, Wa, Ba, zra, nullptr, nullptr, nullptr, 0);
  else
    mfma_body<0, 128, 160>(blockIdx.x - kN, Pb, Wb, Bb, zrb, nullptr, nullptr, nullptr, tb);
}

// ---- merged updates: blocks [0,kN) = u1(t-1) (VAR3), [kN,2kN) = u0(t) ------
__global__ void __launch_bounds__(256, 2) update_pair(StepPtrs Pa, const u16* __restrict__ Wa,
                                                      const float* __restrict__ Ba,
                                                      u16* __restrict__ s1out,
                                                      float* __restrict__ seq,
                                                      float* __restrict__ lastA, int ta,
                                                      StepPtrs Pb, const u16* __restrict__ Wb,
                                                      const float* __restrict__ Bb,
                                                      u16* __restrict__ s0out,
                                                      float* __restrict__ lastB, int tb) {
  if (blockIdx.x < kN)
    mfma_body<3, 64, 256>(blockIdx.x, Pa, Wa, Ba, nullptr, s1out, seq, lastA, ta);
  else
    mfma_body<1, 64, 160>(blockIdx.x - kN, Pb, Wb, Bb, nullptr, s0out, nullptr, lastB, tb);
}

extern "C" void kernel_launch(void* const* d_in, const int* in_sizes, int n_in, void* d_out,
                              int out_size, void* d_ws, size_t ws_size, hipStream_t stream) {
  (void)in_sizes; (void)n_in; (void)out_size; (void)ws_size;
  const float* x   = (const float*)d_in[0];
  const float* ist = (const float*)d_in[1];
  const float* E   = (const float*)d_in[2];
  const float* gw0 = (const float*)d_in[3];
  const float* gb0 = (const float*)d_in[4];
  const float* uw0 = (const float*)d_in[5];
  const float* ub0 = (const float*)d_in[6];
  const float* gw1 = (const float*)d_in[7];
  const float* gb1 = (const float*)d_in[8];
  const float* uw1 = (const float*)d_in[9];
  const float* ub1 = (const float*)d_in[10];
  float* out = (float*)d_out;

  char* base = (char*)d_ws;
  size_t off = 0;
  auto alloc = [&](size_t bytes) {
    char* p = base + off;
    off += (bytes + 1023) & ~(size_t)1023;
    return p;
  };
  u16* Vth = (u16*)alloc((size_t)8192 * kN * 2);
  u16* Ahh = (u16*)alloc((size_t)kN * kN * 2);
  u16* Ax = (u16*)alloc((size_t)kB * kT * kN * 2 * 2);
  u16* Wg0h = (u16*)alloc((size_t)kN * 128 * 160 * 2);
  u16* Wu0h = (u16*)alloc((size_t)kN * 64 * 160 * 2);
  u16* Wg1h = (u16*)alloc((size_t)kN * 128 * 256 * 2);
  u16* Wu1h = (u16*)alloc((size_t)kN * 64 * 256 * 2);
  float* Bg0 = (float*)alloc((size_t)kN * 128 * 4);
  float* Bu0 = (float*)alloc((size_t)kN * 64 * 4);
  float* Bg1 = (float*)alloc((size_t)kN * 128 * 4);
  float* Bu1 = (float*)alloc((size_t)kN * 64 * 4);
  u16* ssA = (u16*)alloc((size_t)BNH * 2 * 2);  // [s0(phase0) | s1] contiguous for cvt
  u16* s0B = (u16*)alloc((size_t)BNH * 2);      // s0 ping-pong buffer
  u16* ddx = (u16*)alloc((size_t)BNH * 2 * 2);  // [dxA | dxB]
  u16* dd = (u16*)alloc((size_t)BNH * 2 * 2);   // [d2 | d3]
  u16* zr0 = (u16*)alloc((size_t)kB * kN * 128 * 2);
  u16* zr1 = (u16*)alloc((size_t)kB * kN * 128 * 2);
  u16* s0buf[2] = {ssA, s0B};
  u16* s1 = ssA + BNH;
  u16* dxA = ddx;
  u16* dxB = ddx + BNH;
  u16* d2 = dd;
  u16* d3 = dd + BNH;

  cvt_state<<<(int)(2 * BNH / 1024), 256, 0, stream>>>(ist, ssA);

  compute_A<<<kN, 256, 0, stream>>>(E, Ahh);
  prep_x<<<dim3(16, 24), 256, 0, stream>>>(x, Vth);
  diff_gemm<<<dim3(12, 8), 512, 0, stream>>>(Ahh, Vth, Ax, 1);

  mkw2<<<dim3(128, 8), 256, 0, stream>>>(E, gw0, Wg0h, 128, 132, 160, 66, 1);
  mkw2<<<dim3(64, 8), 256, 0, stream>>>(E, uw0, Wu0h, 64, 132, 160, 66, 1);
  mkw2<<<dim3(128, 8), 256, 0, stream>>>(E, gw1, Wg1h, 128, 256, 256, 128, 0);
  mkw2<<<dim3(64, 8), 256, 0, stream>>>(E, uw1, Wu1h, 64, 256, 256, 128, 0);
  mkb<<<(kN * 128) / 256, 256, 0, stream>>>(E, gb0, Bg0, 128);
  mkb<<<(kN * 64) / 256, 256, 0, stream>>>(E, ub0, Bu0, 64);
  mkb<<<(kN * 128) / 256, 256, 0, stream>>>(E, gb1, Bg1, 128);
  mkb<<<(kN * 64) / 256, 256, 0, stream>>>(E, ub1, Bu1, 64);

  // bootstrap: d2 = A @ s0_init
  prep_split<<<dim3(16, kB, 1), 256, 0, stream>>>(s0buf[0], nullptr, nullptr, nullptr, Vth);
  diff_gemm<<<dim3(32, 8), 512, 0, stream>>>(Ahh, Vth, d2, 6);

  // head: g0(0), prep(G1,0), G1(0) -> dxB
  {
    StepPtrs Pg0{s0buf[0], s1, zr0, x, Ax, d2, d2, d3};
    mfma_node<0, 128, 160><<<kN, 256, 0, stream>>>(Pg0, Wg0h, Bg0, zr0, nullptr, nullptr,
                                                   nullptr, 0);
    prep_split<<<dim3(16, kB, 1), 256, 0, stream>>>(s0buf[0], nullptr, zr0, nullptr, Vth);
    diff_gemm<<<dim3(32, 8), 512, 0, stream>>>(Ahh, Vth, dxB, 6);
  }

  for (int t = 0; t < kT; ++t) {
    u16* sCur = s0buf[t & 1];
    u16* sNxt = s0buf[(t + 1) & 1];
    // launch 1: updates — u1(t-1) merged with u0(t)
    StepPtrs P1{sCur, s1, zr0, x, Ax, dxB, d2, d3};          // VAR1 at t
    if (t == 0) {
      mfma_node<1, 64, 160><<<kN, 256, 0, stream>>>(P1, Wu0h, Bu0, nullptr, sNxt, nullptr,
                                                    out + OUT0, 0);
    } else {
      StepPtrs P3{sCur, s1, zr1, x, Ax, dxA, d2, dxA};        // VAR3 at t-1 (d3 = dxA)
      update_pair<<<2 * kN, 256, 0, stream>>>(P3, Wu1h, Bu1, s1, out, out + OUT0 + BNH, t - 1,
                                              P1, Wu0h, Bu0, sNxt, out + OUT0, t);
    }
    // launch 2: prep(G2) = [h0(t) ; s1(t)]
    prep_split<<<dim3(16, kB, 2), 256, 0, stream>>>(sNxt, s1, nullptr, nullptr, Vth);
    // launch 3: G2 -> [d2 | d3]
    diff_gemm<<<dim3(64, 8), 512, 0, stream>>>(Ahh, Vth, dd, 6);
    // launch 4: gates — g1(t) merged with g0(t+1)
    StepPtrs P2{sNxt, s1, zr1, x, Ax, d2, d2, d3};           // VAR2 at t
    if (t < kT - 1) {
      StepPtrs P0{sNxt, s1, zr0, x, Ax, d2, d2, d3};         // VAR0 at t+1 (d1 = d2)
      gate_pair<<<2 * kN, 256, 0, stream>>>(P2, Wg1h, Bg1, zr1, P0, Wg0h, Bg0, zr0, t + 1);
    } else {
      mfma_node<2, 128, 256><<<kN, 256, 0, stream>>>(P2, Wg1h, Bg1, zr1, nullptr, nullptr,
                                                     nullptr, 0);
    }
    // launch 5: prep merged = [z1(t)*s1(t) ; z0(t+1)*h0(t)]
    // launch 6: diff -> dxA = G3(t), dxB = G1(t+1)
    if (t < kT - 1) {
      prep_split<<<dim3(16, kB, 2), 256, 0, stream>>>(s1, sNxt, zr1, zr0, Vth);
      diff_gemm<<<dim3(64, 8), 512, 0, stream>>>(Ahh, Vth, ddx, 6);
    } else {
      prep_split<<<dim3(16, kB, 1), 256, 0, stream>>>(s1, nullptr, zr1, nullptr, Vth);
      diff_gemm<<<dim3(32, 8), 512, 0, stream>>>(Ahh, Vth, dxA, 6);
    }
  }
  // tail: u1(11)
  {
    StepPtrs P3{s0buf[0], s1, zr1, x, Ax, dxA, d2, dxA};  // s0 = h0(11) = s0buf[12&1]
    mfma_node<3, 64, 256><<<kN, 256, 0, stream>>>(P3, Wu1h, Bu1, nullptr, s1, out,
                                                  out + OUT0 + BNH, kT - 1);
  }
}